// Round 10
// baseline (35.033 us; speedup 1.0000x reference)
//
#include <hip/hip_runtime.h>

// ConvCapsules2d:
//  activations: [8,32,14,14] f32
//  poses:       [8,32,4,4,14,14] f32   (n,b,i,m,h,w)
//  W_ij:        [32,32,4,4,3,3] f32    (b,c,m,j,k,l)
// Outputs (concatenated flat):
//  acts_out: [8,32,6,6,3,3]                  = 82944 f32
//  V_ji:     [8,32,32,16,6,6,3,3]            = 42467328 f32
// V[n,b,c,i,j,f,g,k,l] = sum_m poses[n,b,i,m,f*2+k,g*2+l] * W[b,c,m,j,k,l]
// r = f*54 + g*9 + k*3 + l ; wo(r) = r%9 ; po(r) = (f*2+k)*14 + (g*2+l)
//
// v9 = v8 structure + register-blocked r-quads: thread computes 4 consecutive
// r for all 16 ij (64 outputs) and stores 16 global_store_dwordx4; lanes carry
// consecutive q -> each wave-store is a contiguous 1024B full-line burst.
// LDS cost unchanged vs v8 (~0.5 b128/output); store instrs 4x fewer.

#define RLEN 324
#define ACTS_OUT 82944
#define PSTRIDE 20          // dwords per padded row (16 data + 4 pad)
#define CPB 8               // c's per block
#define QUADS (CPB * 81)    // 648 r-quad items per block

__device__ __forceinline__ int po_of(int r) {
    int f = r / 54;  int r1 = r - f * 54;
    int g = r1 / 9;  int r2 = r1 - g * 9;
    int k = r2 / 3;  int l  = r2 - k * 3;
    return (f * 2 + k) * 14 + (g * 2 + l);
}

// grid = 1024: bid = nb*4 + cq ; block covers c = cq*8 .. cq*8+7
__global__ __launch_bounds__(256, 4) void v9_kernel(const float* __restrict__ act,
                                                    const float* __restrict__ poses,
                                                    const float* __restrict__ W,
                                                    float* __restrict__ out) {
    __shared__ float    Pl2[196 * PSTRIDE];     // Pl2[po][i*4+m], 15.7 KB
    __shared__ float    Wall[CPB][9 * PSTRIDE]; // Wall[cl][wo][m*4+j], 5.8 KB
    __shared__ unsigned tbl[RLEN];              // po | wo<<16

    const int bid = blockIdx.x;
    const int nb  = bid >> 2;                   // n*32 + b
    const int cq  = bid & 3;
    const int b   = nb & 31;
    const int tid = threadIdx.x;

    // ---- stage poses[n,b] transposed (once per block)
    const float* pn = poses + (size_t)nb * 3136;
    for (int t = tid; t < 784; t += 256) {
        int i  = t / 196;
        int po = t - i * 196;
        float4 v;
        v.x = pn[(i * 4 + 0) * 196 + po];
        v.y = pn[(i * 4 + 1) * 196 + po];
        v.z = pn[(i * 4 + 2) * 196 + po];
        v.w = pn[(i * 4 + 3) * 196 + po];
        *(float4*)&Pl2[po * PSTRIDE + i * 4] = v;
    }
    // ---- stage W[b, cq*8 .. cq*8+7] transposed: Wall[cl][wo][m*4+j]
    for (int t = tid; t < CPB * 36; t += 256) {
        int cl = t / 36;
        int s  = t - cl * 36;
        int wo = s >> 2, m = s & 3;
        const float* wb = W + ((size_t)(b * 32 + cq * CPB + cl)) * 144 + m * 36 + wo;
        float4 v;
        v.x = wb[0 * 9];
        v.y = wb[1 * 9];
        v.z = wb[2 * 9];
        v.w = wb[3 * 9];
        *(float4*)&Wall[cl][wo * PSTRIDE + m * 4] = v;
    }
    // ---- packed (po, wo) table
    for (int r = tid; r < RLEN; r += 256)
        tbl[r] = (unsigned)po_of(r) | ((unsigned)(r % 9) << 16);
    __syncthreads();

    // ---- fused acts_out gather (only cq==0 blocks)
    if (cq == 0) {
        const float* an = act + (size_t)nb * 196;
        for (int a = tid; a < RLEN; a += 256)
            out[nb * RLEN + a] = an[tbl[a] & 0xffffu];
    }

    // ---- main loop: one r-quad (4 consecutive r) x 16 ij per item
    for (int item = tid; item < QUADS; item += 256) {
        int cl = item / 81;
        int q  = item - cl * 81;

        uint4 pk = *(const uint4*)&tbl[q * 4];   // r = 4q+e
        const float* Wb = Wall[cl];

        float o[4][16];   // [e][i*4+j]
        #pragma unroll
        for (int e = 0; e < 4; ++e) {
            unsigned pe = (e == 0) ? pk.x : (e == 1) ? pk.y : (e == 2) ? pk.z : pk.w;
            int po = (int)(pe & 0xffffu);
            int wo = (int)(pe >> 16);
            const float* Pb = &Pl2[po * PSTRIDE];
            const float* Wc = &Wb[wo * PSTRIDE];
            float4 p0 = *(const float4*)&Pb[0];    // i=0: m0..3
            float4 p1 = *(const float4*)&Pb[4];
            float4 p2 = *(const float4*)&Pb[8];
            float4 p3 = *(const float4*)&Pb[12];
            float4 w0 = *(const float4*)&Wc[0];    // m=0: j0..3
            float4 w1 = *(const float4*)&Wc[4];
            float4 w2 = *(const float4*)&Wc[8];
            float4 w3 = *(const float4*)&Wc[12];
            #pragma unroll
            for (int i = 0; i < 4; ++i) {
                float4 pi = (i == 0) ? p0 : (i == 1) ? p1 : (i == 2) ? p2 : p3;
                o[e][i * 4 + 0] = pi.x * w0.x + pi.y * w1.x + pi.z * w2.x + pi.w * w3.x;
                o[e][i * 4 + 1] = pi.x * w0.y + pi.y * w1.y + pi.z * w2.y + pi.w * w3.y;
                o[e][i * 4 + 2] = pi.x * w0.z + pi.y * w1.z + pi.z * w2.z + pi.w * w3.z;
                o[e][i * 4 + 3] = pi.x * w0.w + pi.y * w1.w + pi.z * w2.w + pi.w * w3.w;
            }
        }

        // 16 dwordx4 stores; lanes have consecutive q -> 1024B contiguous bursts
        float* ob = out + ACTS_OUT + ((size_t)(nb * 32 + cq * CPB + cl)) * 5184 + q * 4;
        #pragma unroll
        for (int ij = 0; ij < 16; ++ij) {
            float4 v = make_float4(o[0][ij], o[1][ij], o[2][ij], o[3][ij]);
            *(float4*)&ob[ij * RLEN] = v;
        }
    }
}

extern "C" void kernel_launch(void* const* d_in, const int* in_sizes, int n_in,
                              void* d_out, int out_size, void* d_ws, size_t ws_size,
                              hipStream_t stream) {
    const float* act   = (const float*)d_in[0];
    const float* poses = (const float*)d_in[1];
    const float* W     = (const float*)d_in[2];
    float* out = (float*)d_out;

    v9_kernel<<<1024, 256, 0, stream>>>(act, poses, W, out);
}